// Round 6
// baseline (147.629 us; speedup 1.0000x reference)
//
#include <hip/hip_runtime.h>

// ---------- types ----------
typedef __bf16 v8bf __attribute__((ext_vector_type(8)));
typedef float  v4f  __attribute__((ext_vector_type(4)));
typedef unsigned short us8 __attribute__((ext_vector_type(8)));

// ---------- helpers ----------
__device__ __forceinline__ unsigned short f2bf(float f) {
  unsigned u = __builtin_bit_cast(unsigned, f);
  return (unsigned short)((u + 0x7FFFu + ((u >> 16) & 1u)) >> 16);
}
__device__ __forceinline__ float bf2f(unsigned short s) {
  return __builtin_bit_cast(float, (unsigned)s << 16);
}
__device__ __forceinline__ void gl_lds16(const void* g, void* l) {
  __builtin_amdgcn_global_load_lds(
      (__attribute__((address_space(1))) void*)(void*)g,
      (__attribute__((address_space(3))) void*)l, 16, 0, 0);
}

// ---------- conversion kernels ----------
// Split fp32 into bf16 hi/lo, K-concatenated [rows][2304]:
// lo_slot==1 (x):  [hi | lo | hi];  lo_slot==2 (Wp): [hi | hi | lo]
// Split-K z-slices then compute: z0 hi*hi, z1 lo*hi, z2 hi*lo.
__global__ void split_hl(const float4* __restrict__ in, unsigned short* __restrict__ out,
                         int ncol4, int lo_slot) {
  const int i = blockIdx.x * blockDim.x + threadIdx.x;
  const float4 v = in[i];
  const int row = i / ncol4;
  const int col = (i - row * ncol4) * 4;
  ushort4 hi = make_ushort4(f2bf(v.x), f2bf(v.y), f2bf(v.z), f2bf(v.w));
  ushort4 lo = make_ushort4(f2bf(v.x - bf2f(hi.x)), f2bf(v.y - bf2f(hi.y)),
                            f2bf(v.z - bf2f(hi.z)), f2bf(v.w - bf2f(hi.w)));
  unsigned short* base = out + (size_t)row * 2304 + col;
  *(ushort4*)(base)        = hi;
  *(ushort4*)(base + 768)  = (lo_slot == 1) ? lo : hi;
  *(ushort4*)(base + 1536) = (lo_slot == 1) ? hi : lo;
}

__global__ void conv_bf16(const float4* __restrict__ in, ushort4* __restrict__ out) {
  const int i = blockIdx.x * blockDim.x + threadIdx.x;
  const float4 v = in[i];
  out[i] = make_ushort4(f2bf(v.x), f2bf(v.y), f2bf(v.z), f2bf(v.w));
}

// ---------- GEMM: Cz[m,n] = sum_k A[m,k+z*Ksub]*B[n,k+z*Ksub], bf16 in, fp32 out ----------
// m97 structure: 128x128 tile, BK=32, 4 waves, each wave 64x64 via 4x4 of 16x16x32 MFMA
// (lowest LDS-bytes/FLOP = only shape under the ~85 B/cyc/CU LDS ceiling at MFMA rate).
// Split-K via grid.z -> separate partial buffers (C + z*zstride), no atomics.
__global__ __launch_bounds__(256) void gemm_bt(
    const unsigned short* __restrict__ A, int lda,
    const unsigned short* __restrict__ B, int ldb,
    float* __restrict__ C, int ldc, size_t zstride,
    int Ksub, int tilesN) {
  const int t = threadIdx.x;
  const int bm = blockIdx.x / tilesN;
  const int bn = blockIdx.x % tilesN;
  const int z  = blockIdx.z;
  A += (size_t)z * Ksub;
  B += (size_t)z * Ksub;
  C += (size_t)z * zstride;

  const int wave = t >> 6, lane = t & 63;
  const int quad = lane >> 4, l16 = lane & 15;
  const int wm = (wave >> 1) * 64, wn = (wave & 1) * 64;

  __shared__ __align__(16) unsigned short As[128 * 32];
  __shared__ __align__(16) unsigned short Bs[128 * 32];

  const int srow = t >> 2;          // 0..63
  const int scol = (t & 3) * 8;     // 0,8,16,24
  const unsigned short* Ag = A + (size_t)(bm * 128 + srow) * lda + scol;
  const unsigned short* Bg = B + (size_t)(bn * 128 + srow) * ldb + scol;
  unsigned short* Al = &As[t * 8];
  unsigned short* Bl = &Bs[t * 8];

  v4f acc[4][4];
#pragma unroll
  for (int i = 0; i < 4; i++)
#pragma unroll
    for (int j = 0; j < 4; j++) acc[i][j] = (v4f){0.f, 0.f, 0.f, 0.f};

  for (int kt = 0; kt < Ksub; kt += 32) {
    gl_lds16(Ag + kt, Al);
    gl_lds16(Ag + (size_t)64 * lda + kt, Al + 2048);
    gl_lds16(Bg + kt, Bl);
    gl_lds16(Bg + (size_t)64 * ldb + kt, Bl + 2048);
    __syncthreads();
    v8bf af[4], bfr[4];
#pragma unroll
    for (int i = 0; i < 4; i++)
      af[i] = *(const v8bf*)&As[(wm + i * 16 + l16) * 32 + quad * 8];
#pragma unroll
    for (int j = 0; j < 4; j++)
      bfr[j] = *(const v8bf*)&Bs[(wn + j * 16 + l16) * 32 + quad * 8];
#pragma unroll
    for (int i = 0; i < 4; i++)
#pragma unroll
      for (int j = 0; j < 4; j++)
        acc[i][j] = __builtin_amdgcn_mfma_f32_16x16x32_bf16(af[i], bfr[j], acc[i][j], 0, 0, 0);
    __syncthreads();
  }

  const int row0 = bm * 128 + wm + quad * 4;
  const int col0 = bn * 128 + wn + l16;
#pragma unroll
  for (int j = 0; j < 4; j++) {
    const int col = col0 + j * 16;
#pragma unroll
    for (int i = 0; i < 4; i++) {
#pragma unroll
      for (int r = 0; r < 4; r++) {
        C[(size_t)(row0 + i * 16 + r) * ldc + col] = acc[i][j][r];
      }
    }
  }
}

// ---------- quantum head: sum 3 GEMM1 partials, angles -> PauliZ expectations ----------
// expz[0] = prod_{j=1..7} cos(theta_j); expz[w>=1] = prod_{j=0..w} cos(theta_j)
__global__ void quantum_head(const float* __restrict__ proj3,
                             const float* __restrict__ b_proj,
                             const float* __restrict__ theta,
                             unsigned short* __restrict__ EZ) {
  const size_t ZS = (size_t)4096 * 768;
  const int h = blockIdx.x * blockDim.x + threadIdx.x;  // 0..4096*96-1
  const int token = h / 96;
  const int head = h - token * 96;
  const size_t off = (size_t)token * 768 + head * 8;
  const float4 a0 = *(const float4*)(proj3 + off);
  const float4 a1 = *(const float4*)(proj3 + off + 4);
  const float4 q0 = *(const float4*)(proj3 + ZS + off);
  const float4 q1 = *(const float4*)(proj3 + ZS + off + 4);
  const float4 r0 = *(const float4*)(proj3 + 2 * ZS + off);
  const float4 r1 = *(const float4*)(proj3 + 2 * ZS + off + 4);
  const float4 b0 = *(const float4*)(b_proj + head * 8);
  const float4 b1 = *(const float4*)(b_proj + head * 8 + 4);
  float c[8];
  c[0] = cosf(a0.x + q0.x + r0.x + b0.x + theta[0]);
  c[1] = cosf(a0.y + q0.y + r0.y + b0.y + theta[1]);
  c[2] = cosf(a0.z + q0.z + r0.z + b0.z + theta[2]);
  c[3] = cosf(a0.w + q0.w + r0.w + b0.w + theta[3]);
  c[4] = cosf(a1.x + q1.x + r1.x + b1.x + theta[4]);
  c[5] = cosf(a1.y + q1.y + r1.y + b1.y + theta[5]);
  c[6] = cosf(a1.z + q1.z + r1.z + b1.z + theta[6]);
  c[7] = cosf(a1.w + q1.w + r1.w + b1.w + theta[7]);
  float e[8];
  e[0] = c[1] * c[2] * c[3] * c[4] * c[5] * c[6] * c[7];
  float pr = c[0];
#pragma unroll
  for (int w = 1; w < 8; w++) { pr *= c[w]; e[w] = pr; }
  us8 ov;
#pragma unroll
  for (int w = 0; w < 8; w++) ov[w] = f2bf(e[w]);
  *(us8*)(EZ + (size_t)h * 8) = ov;
}

// ---------- sum3: out = o0 + o1 + o2 + bias (float4-vectorized) ----------
__global__ void sum3(const float4* __restrict__ o, float4* __restrict__ out,
                     const float4* __restrict__ bias) {
  const size_t ZS4 = (size_t)4096 * 192;  // float4 elems per z-slice
  const int i = blockIdx.x * blockDim.x + threadIdx.x;
  const float4 a = o[i], b = o[i + ZS4], c = o[i + 2 * ZS4];
  const float4 bv = bias[i % 192];
  out[i] = make_float4(a.x + b.x + c.x + bv.x, a.y + b.y + c.y + bv.y,
                       a.z + b.z + c.z + bv.z, a.w + b.w + c.w + bv.w);
}

// ---------- launch ----------
extern "C" void kernel_launch(void* const* d_in, const int* in_sizes, int n_in,
                              void* d_out, int out_size, void* d_ws, size_t ws_size,
                              hipStream_t stream) {
  const float* x     = (const float*)d_in[0];
  const float* Wp    = (const float*)d_in[1];
  const float* bp    = (const float*)d_in[2];
  const float* theta = (const float*)d_in[3];
  const float* Wcf   = (const float*)d_in[4];
  const float* bc    = (const float*)d_in[5];
  float* out = (float*)d_out;

  const int M = 4096, E = 768;
  const size_t ZS = (size_t)M * E;

  unsigned short* XC = (unsigned short*)d_ws;        // [4096][2304] bf16 (x: hi|lo|hi)
  unsigned short* WC = XC + (size_t)M * 2304;        // [768][2304] bf16  (Wp: hi|hi|lo)
  unsigned short* WB = WC + (size_t)E * 2304;        // [768][768] bf16   (W_comb)
  unsigned short* EZ = WB + (size_t)E * E;           // [4096][768] bf16  (expz)
  float* proj3       = (float*)(EZ + ZS);            // 3x[4096][768] fp32 partials
  float* out3        = proj3 + 3 * ZS;               // 3x[4096][768] fp32 partials

  // conversions
  split_hl<<<3072, 256, 0, stream>>>((const float4*)x, XC, 192, 1);
  split_hl<<<576, 256, 0, stream>>>((const float4*)Wp, WC, 192, 2);
  conv_bf16<<<576, 256, 0, stream>>>((const float4*)Wcf, (ushort4*)WB);

  // GEMM1: proj3[z] = x_term_z @ Wp_term_z^T   (split-K over the 3 hi/lo terms)
  gemm_bt<<<dim3(192, 1, 3), 256, 0, stream>>>(XC, 2304, WC, 2304, proj3, 768, ZS, 768, 6);

  // quantum head: sum partials + b_proj + theta -> expz (bf16)
  quantum_head<<<1536, 256, 0, stream>>>(proj3, bp, theta, EZ);

  // GEMM2: out3[z] = expz @ Wc^T slices  (split-K 3x256)
  gemm_bt<<<dim3(192, 1, 3), 256, 0, stream>>>(EZ, 768, WB, 768, out3, 768, ZS, 256, 6);

  // out = out3[0]+out3[1]+out3[2] + bc
  sum3<<<3072, 256, 0, stream>>>((const float4*)out3, (float4*)out, (const float4*)bc);
}

// Round 7
// 116.695 us; speedup vs baseline: 1.2651x; 1.2651x over previous
//
#include <hip/hip_runtime.h>

// ---------- types ----------
typedef _Float16 v8h __attribute__((ext_vector_type(8)));
typedef float    v4f __attribute__((ext_vector_type(4)));

// ---------- helpers ----------
__device__ __forceinline__ void gl_lds16(const void* g, void* l) {
  __builtin_amdgcn_global_load_lds(
      (__attribute__((address_space(1))) void*)(void*)g,
      (__attribute__((address_space(3))) void*)l, 16, 0, 0);
}

// ---------- conversion: fp32 -> fp16, 8 elems/thread (16B stores) ----------
__global__ void conv_f16(const float4* __restrict__ in, v8h* __restrict__ out) {
  const int i = blockIdx.x * blockDim.x + threadIdx.x;
  const float4 a = in[2 * i];
  const float4 b = in[2 * i + 1];
  v8h o;
  o[0] = (_Float16)a.x; o[1] = (_Float16)a.y; o[2] = (_Float16)a.z; o[3] = (_Float16)a.w;
  o[4] = (_Float16)b.x; o[5] = (_Float16)b.y; o[6] = (_Float16)b.z; o[7] = (_Float16)b.w;
  out[i] = o;
}

// ---------- GEMM: C[m,n] = sum_k A[m,k]*B[n,k] (+bias[n]), fp16 in, fp32 out ----------
// 64x64 tile, BK=32, 4 waves (each wave 32x32 via 2x2 of 16x16x32_f16 MFMA).
// Both GEMMs share this exact shape: M=4096, N=768, K=768 -> 64x12 = 768 blocks
// (3 blocks/CU, the best measured per-iter-effective config). XCD swizzle:
// xcd = blockIdx%8; each XCD gets a contiguous 8-M-tile band, N inner (L2 reuse).
__global__ __launch_bounds__(256) void gemm_f16(
    const _Float16* __restrict__ A, int lda,
    const _Float16* __restrict__ B, int ldb,
    float* __restrict__ C, int ldc,
    int K, const float* __restrict__ bias) {
  const int t = threadIdx.x;
  const int b = blockIdx.x;
  const int xcd = b & 7, slot = b >> 3;      // 768 blocks -> slot 0..95
  const int bm = xcd * 8 + slot / 12;        // 0..63
  const int bn = slot % 12;                  // 0..11

  const int wave = t >> 6, lane = t & 63;
  const int quad = lane >> 4, l16 = lane & 15;
  const int wm = (wave >> 1) * 32, wn = (wave & 1) * 32;

  __shared__ __align__(16) _Float16 As[64 * 32];
  __shared__ __align__(16) _Float16 Bs[64 * 32];

  const int srow = t >> 2;          // 0..63
  const int scol = (t & 3) * 8;     // 0,8,16,24
  const _Float16* Ag = A + (size_t)(bm * 64 + srow) * lda + scol;
  const _Float16* Bg = B + (size_t)(bn * 64 + srow) * ldb + scol;
  _Float16* Al = &As[srow * 32 + scol];
  _Float16* Bl = &Bs[srow * 32 + scol];

  v4f acc[2][2];
#pragma unroll
  for (int i = 0; i < 2; i++)
#pragma unroll
    for (int j = 0; j < 2; j++) acc[i][j] = (v4f){0.f, 0.f, 0.f, 0.f};

  for (int kt = 0; kt < K; kt += 32) {
    gl_lds16(Ag + kt, Al);
    gl_lds16(Bg + kt, Bl);
    __syncthreads();
    v8h af[2], bf[2];
#pragma unroll
    for (int i = 0; i < 2; i++)
      af[i] = *(const v8h*)&As[(wm + i * 16 + l16) * 32 + quad * 8];
#pragma unroll
    for (int j = 0; j < 2; j++)
      bf[j] = *(const v8h*)&Bs[(wn + j * 16 + l16) * 32 + quad * 8];
#pragma unroll
    for (int i = 0; i < 2; i++)
#pragma unroll
      for (int j = 0; j < 2; j++)
        acc[i][j] = __builtin_amdgcn_mfma_f32_16x16x32_f16(af[i], bf[j], acc[i][j], 0, 0, 0);
    __syncthreads();
  }

  const int row0 = bm * 64 + wm + quad * 4;
  const int col0 = bn * 64 + wn + l16;
#pragma unroll
  for (int j = 0; j < 2; j++) {
    const int col = col0 + j * 16;
    const float bv = bias ? bias[col] : 0.f;
#pragma unroll
    for (int i = 0; i < 2; i++) {
#pragma unroll
      for (int r = 0; r < 4; r++) {
        C[(size_t)(row0 + i * 16 + r) * ldc + col] = acc[i][j][r] + bv;
      }
    }
  }
}

// ---------- quantum head: angles -> PauliZ expectations (closed form) ----------
// expz[0] = prod_{j=1..7} cos(theta_j); expz[w>=1] = prod_{j=0..w} cos(theta_j)
__global__ void quantum_head(const float* __restrict__ proj,
                             const float* __restrict__ b_proj,
                             const float* __restrict__ theta,
                             _Float16* __restrict__ EZ) {
  const int h = blockIdx.x * blockDim.x + threadIdx.x;  // 0..4096*96-1
  const int token = h / 96;
  const int head = h - token * 96;
  const size_t off = (size_t)token * 768 + head * 8;
  const float4 p0 = *(const float4*)(proj + off);
  const float4 p1 = *(const float4*)(proj + off + 4);
  const float4 b0 = *(const float4*)(b_proj + head * 8);
  const float4 b1 = *(const float4*)(b_proj + head * 8 + 4);
  float c[8];
  c[0] = cosf(p0.x + b0.x + theta[0]);
  c[1] = cosf(p0.y + b0.y + theta[1]);
  c[2] = cosf(p0.z + b0.z + theta[2]);
  c[3] = cosf(p0.w + b0.w + theta[3]);
  c[4] = cosf(p1.x + b1.x + theta[4]);
  c[5] = cosf(p1.y + b1.y + theta[5]);
  c[6] = cosf(p1.z + b1.z + theta[6]);
  c[7] = cosf(p1.w + b1.w + theta[7]);
  float e[8];
  e[0] = c[1] * c[2] * c[3] * c[4] * c[5] * c[6] * c[7];
  float pr = c[0];
#pragma unroll
  for (int w = 1; w < 8; w++) { pr *= c[w]; e[w] = pr; }
  v8h ov;
#pragma unroll
  for (int w = 0; w < 8; w++) ov[w] = (_Float16)e[w];
  *(v8h*)(EZ + (size_t)h * 8) = ov;
}

// ---------- launch ----------
extern "C" void kernel_launch(void* const* d_in, const int* in_sizes, int n_in,
                              void* d_out, int out_size, void* d_ws, size_t ws_size,
                              hipStream_t stream) {
  const float* x     = (const float*)d_in[0];
  const float* Wp    = (const float*)d_in[1];
  const float* bp    = (const float*)d_in[2];
  const float* theta = (const float*)d_in[3];
  const float* Wcf   = (const float*)d_in[4];
  const float* bc    = (const float*)d_in[5];
  float* out = (float*)d_out;

  const int M = 4096, E = 768;
  const size_t ME = (size_t)M * E;   // 3,145,728
  const size_t EE = (size_t)E * E;   // 589,824

  _Float16* XH  = (_Float16*)d_ws;        // [4096][768] fp16 x
  _Float16* WPH = XH + ME;                // [768][768] fp16 W_proj
  _Float16* WCH = WPH + EE;               // [768][768] fp16 W_comb
  _Float16* EZ  = WCH + EE;               // [4096][768] fp16 expz
  float* proj   = (float*)(EZ + ME);      // [4096][768] fp32

  // conversions (8 elems/thread)
  conv_f16<<<(int)(ME / 8 / 256), 256, 0, stream>>>((const float4*)x, (v8h*)XH);
  conv_f16<<<(int)(EE / 8 / 256), 256, 0, stream>>>((const float4*)Wp, (v8h*)WPH);
  conv_f16<<<(int)(EE / 8 / 256), 256, 0, stream>>>((const float4*)Wcf, (v8h*)WCH);

  // GEMM1: proj = x @ Wp^T   (fp16, K=768, 768 blocks)
  gemm_f16<<<768, 256, 0, stream>>>(XH, 768, WPH, 768, proj, 768, 768, nullptr);

  // quantum head: angles = proj + b_proj + theta -> expz (fp16)
  quantum_head<<<1536, 256, 0, stream>>>(proj, bp, theta, EZ);

  // GEMM2: out = expz @ Wc^T + bc   (fp16, K=768, 768 blocks)
  gemm_f16<<<768, 256, 0, stream>>>(EZ, 768, WCH, 768, out, 768, 768, bc);
}

// Round 8
// 111.521 us; speedup vs baseline: 1.3238x; 1.0464x over previous
//
#include <hip/hip_runtime.h>

// ---------- types ----------
typedef _Float16 v8h __attribute__((ext_vector_type(8)));
typedef float    v4f __attribute__((ext_vector_type(4)));

// ---------- helpers ----------
__device__ __forceinline__ void gl_lds16(const void* g, void* l) {
  __builtin_amdgcn_global_load_lds(
      (__attribute__((address_space(1))) void*)(void*)g,
      (__attribute__((address_space(3))) void*)l, 16, 0, 0);
}

// ---------- conversion: both weights fp32 -> fp16 in one launch ----------
__global__ void conv_w(const float4* __restrict__ wp, const float4* __restrict__ wc,
                       v8h* __restrict__ op, v8h* __restrict__ oc) {
  const int n = 73728;  // 768*768/8
  int i = blockIdx.x * blockDim.x + threadIdx.x;  // 0..2n-1
  const float4* src = (i < n) ? wp : wc;
  v8h* dst = (i < n) ? op : oc;
  const int j = (i < n) ? i : i - n;
  const float4 a = src[2 * j];
  const float4 b = src[2 * j + 1];
  v8h o;
  o[0] = (_Float16)a.x; o[1] = (_Float16)a.y; o[2] = (_Float16)a.z; o[3] = (_Float16)a.w;
  o[4] = (_Float16)b.x; o[5] = (_Float16)b.y; o[6] = (_Float16)b.z; o[7] = (_Float16)b.w;
  dst[j] = o;
}

// ---------- GEMM1 + quantum head, fused ----------
// proj-tile[64x64] = X[64x768] @ Wp^T tile, then (in-epilogue, via LDS):
// angles = proj + b_proj + theta; expz via cos prefix-products; write fp16 EZ.
// A 64-col tile covers 8 complete heads (8 wires each) -> fusion is tile-local.
// A staged from fp32 via register convert + ds_write_b128; B via gl_lds16.
// Grid: 64 M-tiles x 12 N-tiles = 768 blocks (3/CU). XCD swizzle as before.
__global__ __launch_bounds__(256) void gemm1_qh(
    const float* __restrict__ X,          // [4096][768] fp32
    const _Float16* __restrict__ B,       // [768][768] fp16 (W_proj)
    const float* __restrict__ bp,         // [768]
    const float* __restrict__ theta,      // [8]
    _Float16* __restrict__ EZ) {          // [4096][768] fp16
  const int t = threadIdx.x;
  const int b = blockIdx.x;
  const int xcd = b & 7, slot = b >> 3;
  const int bm = xcd * 8 + slot / 12;
  const int bn = slot % 12;

  const int wave = t >> 6, lane = t & 63;
  const int quad = lane >> 4, l16 = lane & 15;
  const int wm = (wave >> 1) * 32, wn = (wave & 1) * 32;

  // staging (8 KB) and epilogue C-tile (64x68 fp32 = 17 KB) share this buffer
  __shared__ __align__(16) unsigned char smem[64 * 68 * 4];
  _Float16* As = (_Float16*)smem;
  _Float16* Bs = (_Float16*)(smem + 4096);
  float* Cs = (float*)smem;

  const float4 th0 = *(const float4*)theta;
  const float4 th1 = *(const float4*)(theta + 4);

  const int srow = t >> 2, sg = t & 3;
  const float* Xg = X + (size_t)(bm * 64 + srow) * 768 + sg * 8;
  const _Float16* Bg = B + (size_t)(bn * 64 + srow) * 768 + sg * 8;
  _Float16* Al = &As[t * 8];
  _Float16* Bl = &Bs[t * 8];

  v4f acc[2][2];
#pragma unroll
  for (int i = 0; i < 2; i++)
#pragma unroll
    for (int j = 0; j < 2; j++) acc[i][j] = (v4f){0.f, 0.f, 0.f, 0.f};

  for (int kt = 0; kt < 768; kt += 32) {
    const float4 a0 = *(const float4*)(Xg + kt);
    const float4 a1 = *(const float4*)(Xg + kt + 4);
    gl_lds16(Bg + kt, Bl);
    v8h av;
    av[0] = (_Float16)a0.x; av[1] = (_Float16)a0.y; av[2] = (_Float16)a0.z; av[3] = (_Float16)a0.w;
    av[4] = (_Float16)a1.x; av[5] = (_Float16)a1.y; av[6] = (_Float16)a1.z; av[7] = (_Float16)a1.w;
    *(v8h*)Al = av;
    __syncthreads();
    v8h af[2], bf[2];
#pragma unroll
    for (int i = 0; i < 2; i++)
      af[i] = *(const v8h*)&As[(wm + i * 16 + l16) * 32 + quad * 8];
#pragma unroll
    for (int j = 0; j < 2; j++)
      bf[j] = *(const v8h*)&Bs[(wn + j * 16 + l16) * 32 + quad * 8];
#pragma unroll
    for (int i = 0; i < 2; i++)
#pragma unroll
      for (int j = 0; j < 2; j++)
        acc[i][j] = __builtin_amdgcn_mfma_f32_16x16x32_f16(af[i], bf[j], acc[i][j], 0, 0, 0);
    __syncthreads();
  }

  // ---- epilogue: acc -> LDS (stride 68), then QH per row-head ----
  const int r0 = wm + quad * 4;
  const int c0 = wn + l16;
#pragma unroll
  for (int j = 0; j < 2; j++)
#pragma unroll
    for (int i = 0; i < 2; i++)
#pragma unroll
      for (int r = 0; r < 4; r++)
        Cs[(r0 + i * 16 + r) * 68 + c0 + j * 16] = acc[i][j][r];
  __syncthreads();

#pragma unroll
  for (int s = 0; s < 2; s++) {
    const int idx = t + s * 256;          // 0..511
    const int row = idx >> 3, h = idx & 7;
    const int gcol = bn * 64 + h * 8;
    const float* cr = &Cs[row * 68 + h * 8];
    const float4 q0 = *(const float4*)cr;
    const float4 q1 = *(const float4*)(cr + 4);
    const float4 b0 = *(const float4*)(bp + gcol);
    const float4 b1 = *(const float4*)(bp + gcol + 4);
    float c[8];
    c[0] = cosf(q0.x + b0.x + th0.x);
    c[1] = cosf(q0.y + b0.y + th0.y);
    c[2] = cosf(q0.z + b0.z + th0.z);
    c[3] = cosf(q0.w + b0.w + th0.w);
    c[4] = cosf(q1.x + b1.x + th1.x);
    c[5] = cosf(q1.y + b1.y + th1.y);
    c[6] = cosf(q1.z + b1.z + th1.z);
    c[7] = cosf(q1.w + b1.w + th1.w);
    float e[8];
    e[0] = c[1] * c[2] * c[3] * c[4] * c[5] * c[6] * c[7];
    float pr = c[0];
#pragma unroll
    for (int w = 1; w < 8; w++) { pr *= c[w]; e[w] = pr; }
    v8h ov;
#pragma unroll
    for (int w = 0; w < 8; w++) ov[w] = (_Float16)e[w];
    *(v8h*)(EZ + (size_t)(bm * 64 + row) * 768 + gcol) = ov;
  }
}

// ---------- GEMM2: out = EZ @ Wc^T + bc, fp16 in, fp32 out ----------
__global__ __launch_bounds__(256) void gemm_f16(
    const _Float16* __restrict__ A, int lda,
    const _Float16* __restrict__ B, int ldb,
    float* __restrict__ C, int ldc,
    int K, const float* __restrict__ bias) {
  const int t = threadIdx.x;
  const int b = blockIdx.x;
  const int xcd = b & 7, slot = b >> 3;
  const int bm = xcd * 8 + slot / 12;
  const int bn = slot % 12;

  const int wave = t >> 6, lane = t & 63;
  const int quad = lane >> 4, l16 = lane & 15;
  const int wm = (wave >> 1) * 32, wn = (wave & 1) * 32;

  __shared__ __align__(16) _Float16 As[64 * 32];
  __shared__ __align__(16) _Float16 Bs[64 * 32];

  const int srow = t >> 2;
  const int scol = (t & 3) * 8;
  const _Float16* Ag = A + (size_t)(bm * 64 + srow) * lda + scol;
  const _Float16* Bg = B + (size_t)(bn * 64 + srow) * ldb + scol;
  _Float16* Al = &As[srow * 32 + scol];
  _Float16* Bl = &Bs[srow * 32 + scol];

  v4f acc[2][2];
#pragma unroll
  for (int i = 0; i < 2; i++)
#pragma unroll
    for (int j = 0; j < 2; j++) acc[i][j] = (v4f){0.f, 0.f, 0.f, 0.f};

  for (int kt = 0; kt < K; kt += 32) {
    gl_lds16(Ag + kt, Al);
    gl_lds16(Bg + kt, Bl);
    __syncthreads();
    v8h af[2], bf[2];
#pragma unroll
    for (int i = 0; i < 2; i++)
      af[i] = *(const v8h*)&As[(wm + i * 16 + l16) * 32 + quad * 8];
#pragma unroll
    for (int j = 0; j < 2; j++)
      bf[j] = *(const v8h*)&Bs[(wn + j * 16 + l16) * 32 + quad * 8];
#pragma unroll
    for (int i = 0; i < 2; i++)
#pragma unroll
      for (int j = 0; j < 2; j++)
        acc[i][j] = __builtin_amdgcn_mfma_f32_16x16x32_f16(af[i], bf[j], acc[i][j], 0, 0, 0);
    __syncthreads();
  }

  const int row0 = bm * 64 + wm + quad * 4;
  const int col0 = bn * 64 + wn + l16;
#pragma unroll
  for (int j = 0; j < 2; j++) {
    const int col = col0 + j * 16;
    const float bv = bias ? bias[col] : 0.f;
#pragma unroll
    for (int i = 0; i < 2; i++) {
#pragma unroll
      for (int r = 0; r < 4; r++) {
        C[(size_t)(row0 + i * 16 + r) * ldc + col] = acc[i][j][r] + bv;
      }
    }
  }
}

// ---------- launch ----------
extern "C" void kernel_launch(void* const* d_in, const int* in_sizes, int n_in,
                              void* d_out, int out_size, void* d_ws, size_t ws_size,
                              hipStream_t stream) {
  const float* x     = (const float*)d_in[0];
  const float* Wp    = (const float*)d_in[1];
  const float* bp    = (const float*)d_in[2];
  const float* theta = (const float*)d_in[3];
  const float* Wcf   = (const float*)d_in[4];
  const float* bc    = (const float*)d_in[5];
  float* out = (float*)d_out;

  const int M = 4096, E = 768;
  const size_t ME = (size_t)M * E;
  const size_t EE = (size_t)E * E;

  _Float16* WPH = (_Float16*)d_ws;        // [768][768] fp16 W_proj
  _Float16* WCH = WPH + EE;               // [768][768] fp16 W_comb
  _Float16* EZ  = WCH + EE;               // [4096][768] fp16 expz

  // both weight conversions in one launch (2*EE/8 threads)
  conv_w<<<(int)(2 * EE / 8 / 256), 256, 0, stream>>>(
      (const float4*)Wp, (const float4*)Wcf, (v8h*)WPH, (v8h*)WCH);

  // GEMM1 fused with quantum head: x(fp32) @ Wp^T -> angles -> expz (fp16)
  gemm1_qh<<<768, 256, 0, stream>>>(x, WPH, bp, theta, EZ);

  // GEMM2: out = expz @ Wc^T + bc
  gemm_f16<<<768, 256, 0, stream>>>(EZ, 768, WCH, 768, out, 768, 768, bc);
}

// Round 9
// 99.281 us; speedup vs baseline: 1.4870x; 1.1233x over previous
//
#include <hip/hip_runtime.h>

// ---------- types ----------
typedef _Float16 v8h __attribute__((ext_vector_type(8)));
typedef float    v4f __attribute__((ext_vector_type(4)));

// ---------- helpers ----------
__device__ __forceinline__ void gl_lds16(const void* g, void* l) {
  __builtin_amdgcn_global_load_lds(
      (__attribute__((address_space(1))) void*)(void*)g,
      (__attribute__((address_space(3))) void*)l, 16, 0, 0);
}

// ---------- conversion: both weights fp32 -> fp16 in one launch ----------
__global__ void conv_w(const float4* __restrict__ wp, const float4* __restrict__ wc,
                       v8h* __restrict__ op, v8h* __restrict__ oc) {
  const int n = 73728;  // 768*768/8
  int i = blockIdx.x * blockDim.x + threadIdx.x;  // 0..2n-1
  const float4* src = (i < n) ? wp : wc;
  v8h* dst = (i < n) ? op : oc;
  const int j = (i < n) ? i : i - n;
  const float4 a = src[2 * j];
  const float4 b = src[2 * j + 1];
  v8h o;
  o[0] = (_Float16)a.x; o[1] = (_Float16)a.y; o[2] = (_Float16)a.z; o[3] = (_Float16)a.w;
  o[4] = (_Float16)b.x; o[5] = (_Float16)b.y; o[6] = (_Float16)b.z; o[7] = (_Float16)b.w;
  dst[j] = o;
}

// ============================================================================
// GEMM structure (both kernels): BM=64, BN=64, BK=128, 6 K-iters (K=768).
// 4 waves, each 32x32 via 2x2 of 16x16x32_f16 MFMA over 4 K-chunks per iter.
// LDS tiles 64x128 fp16, XOR-swizzled: element (row, cg) stored at phys
// colgroup cg ^ (row & 15)  (cg = 8-elem group). Staging keeps the gl_lds
// wave-uniform LDS pattern (base + t*16B) and permutes the GLOBAL address;
// fragment reads apply the same XOR -> conflict-free (32 B/bank per b128).
// Grid: 64 M-tiles x 12 N-tiles = 768 blocks (3/CU). XCD swizzle as before.
// ============================================================================

// ---------- GEMM1 + quantum head, fused ----------
__global__ __launch_bounds__(256) void gemm1_qh(
    const float* __restrict__ X,          // [4096][768] fp32
    const _Float16* __restrict__ B,       // [768][768] fp16 (W_proj)
    const float* __restrict__ bp,         // [768]
    const float* __restrict__ theta,      // [8]
    _Float16* __restrict__ EZ) {          // [4096][768] fp16
  const int t = threadIdx.x;
  const int b = blockIdx.x;
  const int xcd = b & 7, slot = b >> 3;
  const int bm = xcd * 8 + slot / 12;
  const int bn = slot % 12;

  const int wave = t >> 6, lane = t & 63;
  const int quad = lane >> 4, l16 = lane & 15;
  const int wm = (wave >> 1) * 32, wn = (wave & 1) * 32;

  __shared__ __align__(16) unsigned char smem[32768];
  _Float16* As = (_Float16*)smem;            // 64 x 128 (swizzled)
  _Float16* Bs = (_Float16*)(smem + 16384);  // 64 x 128 (swizzled)
  float* Cs = (float*)smem;                  // epilogue reuse: 64 x 68 fp32

  const float4 th0 = *(const float4*)theta;
  const float4 th1 = *(const float4*)(theta + 4);

  const int tr = t >> 4;          // 0..15 (row-in-group)
  const int tc = t & 15;          // col-group
  const int cgl = tc ^ tr;        // swizzled logical col-group for staging

  const float*    Xg = X + (size_t)(bm * 64 + tr) * 768 + cgl * 8;
  const _Float16* Bg = B + (size_t)(bn * 64 + tr) * 768 + cgl * 8;

  v4f acc[2][2];
#pragma unroll
  for (int i = 0; i < 2; i++)
#pragma unroll
    for (int j = 0; j < 2; j++) acc[i][j] = (v4f){0.f, 0.f, 0.f, 0.f};

  for (int kt = 0; kt < 768; kt += 128) {
    // stage B (async direct-to-LDS), then A (fp32->fp16 via regs) overlapping
#pragma unroll
    for (int c = 0; c < 4; c++)
      gl_lds16(Bg + (size_t)c * 16 * 768 + kt, &Bs[c * 2048 + t * 8]);
#pragma unroll
    for (int c = 0; c < 4; c++) {
      const float* p = Xg + (size_t)c * 16 * 768 + kt;
      const float4 a0 = *(const float4*)p;
      const float4 a1 = *(const float4*)(p + 4);
      v8h av;
      av[0] = (_Float16)a0.x; av[1] = (_Float16)a0.y; av[2] = (_Float16)a0.z; av[3] = (_Float16)a0.w;
      av[4] = (_Float16)a1.x; av[5] = (_Float16)a1.y; av[6] = (_Float16)a1.z; av[7] = (_Float16)a1.w;
      *(v8h*)&As[c * 2048 + t * 8] = av;
    }
    __syncthreads();
#pragma unroll
    for (int q = 0; q < 4; q++) {
      v8h af[2], bf[2];
#pragma unroll
      for (int i = 0; i < 2; i++)
        af[i] = *(const v8h*)&As[(wm + i * 16 + l16) * 128 + (((q * 4 + quad) ^ l16) * 8)];
#pragma unroll
      for (int j = 0; j < 2; j++)
        bf[j] = *(const v8h*)&Bs[(wn + j * 16 + l16) * 128 + (((q * 4 + quad) ^ l16) * 8)];
#pragma unroll
      for (int i = 0; i < 2; i++)
#pragma unroll
        for (int j = 0; j < 2; j++)
          acc[i][j] = __builtin_amdgcn_mfma_f32_16x16x32_f16(af[i], bf[j], acc[i][j], 0, 0, 0);
    }
    __syncthreads();
  }

  // ---- epilogue: acc -> LDS (stride 68), then quantum head per row-head ----
  const int r0 = wm + quad * 4;
  const int c0 = wn + l16;
#pragma unroll
  for (int j = 0; j < 2; j++)
#pragma unroll
    for (int i = 0; i < 2; i++)
#pragma unroll
      for (int r = 0; r < 4; r++)
        Cs[(r0 + i * 16 + r) * 68 + c0 + j * 16] = acc[i][j][r];
  __syncthreads();

#pragma unroll
  for (int s = 0; s < 2; s++) {
    const int idx = t + s * 256;          // 0..511 = 64 rows x 8 heads
    const int row = idx >> 3, h = idx & 7;
    const int gcol = bn * 64 + h * 8;
    const float* cr = &Cs[row * 68 + h * 8];
    const float4 q0 = *(const float4*)cr;
    const float4 q1 = *(const float4*)(cr + 4);
    const float4 b0 = *(const float4*)(bp + gcol);
    const float4 b1 = *(const float4*)(bp + gcol + 4);
    float c[8];
    c[0] = cosf(q0.x + b0.x + th0.x);
    c[1] = cosf(q0.y + b0.y + th0.y);
    c[2] = cosf(q0.z + b0.z + th0.z);
    c[3] = cosf(q0.w + b0.w + th0.w);
    c[4] = cosf(q1.x + b1.x + th1.x);
    c[5] = cosf(q1.y + b1.y + th1.y);
    c[6] = cosf(q1.z + b1.z + th1.z);
    c[7] = cosf(q1.w + b1.w + th1.w);
    float e[8];
    e[0] = c[1] * c[2] * c[3] * c[4] * c[5] * c[6] * c[7];
    float pr = c[0];
#pragma unroll
    for (int w = 1; w < 8; w++) { pr *= c[w]; e[w] = pr; }
    v8h ov;
#pragma unroll
    for (int w = 0; w < 8; w++) ov[w] = (_Float16)e[w];
    *(v8h*)(EZ + (size_t)(bm * 64 + row) * 768 + gcol) = ov;
  }
}

// ---------- GEMM2: out = EZ @ Wc^T + bc, fp16 in, fp32 out ----------
__global__ __launch_bounds__(256) void gemm2(
    const _Float16* __restrict__ A,       // [4096][768] fp16 (EZ)
    const _Float16* __restrict__ B,       // [768][768] fp16 (W_comb)
    float* __restrict__ C,                // [4096][768] fp32
    const float* __restrict__ bias) {
  const int t = threadIdx.x;
  const int b = blockIdx.x;
  const int xcd = b & 7, slot = b >> 3;
  const int bm = xcd * 8 + slot / 12;
  const int bn = slot % 12;

  const int wave = t >> 6, lane = t & 63;
  const int quad = lane >> 4, l16 = lane & 15;
  const int wm = (wave >> 1) * 32, wn = (wave & 1) * 32;

  __shared__ __align__(16) _Float16 As[64 * 128];
  __shared__ __align__(16) _Float16 Bs[64 * 128];

  const int tr = t >> 4;
  const int tc = t & 15;
  const int cgl = tc ^ tr;

  const _Float16* Ag = A + (size_t)(bm * 64 + tr) * 768 + cgl * 8;
  const _Float16* Bg = B + (size_t)(bn * 64 + tr) * 768 + cgl * 8;

  v4f acc[2][2];
#pragma unroll
  for (int i = 0; i < 2; i++)
#pragma unroll
    for (int j = 0; j < 2; j++) acc[i][j] = (v4f){0.f, 0.f, 0.f, 0.f};

  for (int kt = 0; kt < 768; kt += 128) {
#pragma unroll
    for (int c = 0; c < 4; c++) {
      gl_lds16(Ag + (size_t)c * 16 * 768 + kt, &As[c * 2048 + t * 8]);
      gl_lds16(Bg + (size_t)c * 16 * 768 + kt, &Bs[c * 2048 + t * 8]);
    }
    __syncthreads();
#pragma unroll
    for (int q = 0; q < 4; q++) {
      v8h af[2], bf[2];
#pragma unroll
      for (int i = 0; i < 2; i++)
        af[i] = *(const v8h*)&As[(wm + i * 16 + l16) * 128 + (((q * 4 + quad) ^ l16) * 8)];
#pragma unroll
      for (int j = 0; j < 2; j++)
        bf[j] = *(const v8h*)&Bs[(wn + j * 16 + l16) * 128 + (((q * 4 + quad) ^ l16) * 8)];
#pragma unroll
      for (int i = 0; i < 2; i++)
#pragma unroll
        for (int j = 0; j < 2; j++)
          acc[i][j] = __builtin_amdgcn_mfma_f32_16x16x32_f16(af[i], bf[j], acc[i][j], 0, 0, 0);
    }
    __syncthreads();
  }

  const int row0 = bm * 64 + wm + quad * 4;
  const int col0 = bn * 64 + wn + l16;
#pragma unroll
  for (int j = 0; j < 2; j++) {
    const int col = col0 + j * 16;
    const float bv = bias[col];
#pragma unroll
    for (int i = 0; i < 2; i++) {
#pragma unroll
      for (int r = 0; r < 4; r++) {
        C[(size_t)(row0 + i * 16 + r) * 768 + col] = acc[i][j][r] + bv;
      }
    }
  }
}

// ---------- launch ----------
extern "C" void kernel_launch(void* const* d_in, const int* in_sizes, int n_in,
                              void* d_out, int out_size, void* d_ws, size_t ws_size,
                              hipStream_t stream) {
  const float* x     = (const float*)d_in[0];
  const float* Wp    = (const float*)d_in[1];
  const float* bp    = (const float*)d_in[2];
  const float* theta = (const float*)d_in[3];
  const float* Wcf   = (const float*)d_in[4];
  const float* bc    = (const float*)d_in[5];
  float* out = (float*)d_out;

  const int M = 4096, E = 768;
  const size_t ME = (size_t)M * E;
  const size_t EE = (size_t)E * E;

  _Float16* WPH = (_Float16*)d_ws;        // [768][768] fp16 W_proj
  _Float16* WCH = WPH + EE;               // [768][768] fp16 W_comb
  _Float16* EZ  = WCH + EE;               // [4096][768] fp16 expz

  // both weight conversions in one launch
  conv_w<<<(int)(2 * EE / 8 / 256), 256, 0, stream>>>(
      (const float4*)Wp, (const float4*)Wcf, (v8h*)WPH, (v8h*)WCH);

  // GEMM1 fused with quantum head: x(fp32) @ Wp^T -> angles -> expz (fp16)
  gemm1_qh<<<768, 256, 0, stream>>>(x, WPH, bp, theta, EZ);

  // GEMM2: out = expz @ Wc^T + bc
  gemm2<<<768, 256, 0, stream>>>(EZ, WCH, out, bc);
}